// Round 2
// 409.825 us; speedup vs baseline: 1.0062x; 1.0062x over previous
//
#include <hip/hip_runtime.h>

// ImageBuffer: sliding-window gather, re-expressed as a scatter.
//   combined = concat(buffer[16 frames], inputs[128 frames]), frame = H*W*C floats
//   out[b][k] = combined[b + 1 + k]
// Inverted: source frame j (1..143) feeds outputs b in [max(0,j-16), min(127,j-1)],
// k = j-1-b, output-frame index f = b*16 + k = 15*b + j - 1 (stride 15 frames).
// Each chunk of frame j is loaded ONCE into registers and stored up to 16x with
// non-temporal stores: read traffic 402.7 MB -> 28.3 MB, writes pure streaming.
// Native clang vector type (not HIP_vector_type) so __builtin_nontemporal_* accepts it.

typedef float f32x4 __attribute__((ext_vector_type(4)));

constexpr int BATCH     = 128;
constexpr int KBUF      = 16;
constexpr int FRAME_F32 = 128 * 128 * 3;       // 49152 floats per frame
constexpr int FRAME_F4  = FRAME_F32 / 4;       // 12288 float4 per frame
constexpr int BLOCK     = 256;
constexpr int VEC       = 2;                   // float4 per thread
constexpr int CHUNK_F4  = BLOCK * VEC;         // 512 float4 per block
constexpr int CHUNKS    = FRAME_F4 / CHUNK_F4; // 24 chunks per source frame
constexpr int NSRC      = BATCH + KBUF - 1;    // source frames j = 1..143 (j=0 unused)

__global__ __launch_bounds__(BLOCK)
void ImageBuffer_86784109183359_kernel(const f32x4* __restrict__ inputs,
                                       const f32x4* __restrict__ buffer,
                                       f32x4* __restrict__ out) {
    const int j     = blockIdx.x / CHUNKS + 1;        // source frame in `combined`, 1..143
    const int chunk = blockIdx.x % CHUNKS;
    const int off   = chunk * CHUNK_F4 + threadIdx.x; // float4 offset within frame

    // Branch is uniform per block (j is block-constant) — no divergence.
    const f32x4* __restrict__ src =
        (j < KBUF) ? (buffer + (size_t)j * FRAME_F4)
                   : (inputs + (size_t)(j - KBUF) * FRAME_F4);

    const f32x4 v0 = __builtin_nontemporal_load(&src[off]);
    const f32x4 v1 = __builtin_nontemporal_load(&src[off + BLOCK]);

    const int b_lo = (j > KBUF) ? (j - KBUF) : 0;
    const int b_hi = (j - 1 < BATCH - 1) ? (j - 1) : (BATCH - 1);

    // f = 15*b + j - 1; consecutive b steps advance the output frame by 15.
    size_t base = (size_t)(15 * b_lo + j - 1) * FRAME_F4 + off;
    const size_t stride = (size_t)15 * FRAME_F4;

    for (int b = b_lo; b <= b_hi; ++b) {
        __builtin_nontemporal_store(v0, &out[base]);
        __builtin_nontemporal_store(v1, &out[base + BLOCK]);
        base += stride;
    }
}

extern "C" void kernel_launch(void* const* d_in, const int* in_sizes, int n_in,
                              void* d_out, int out_size, void* d_ws, size_t ws_size,
                              hipStream_t stream) {
    const f32x4* inputs = (const f32x4*)d_in[0];  // [128,128,128,3] fp32
    const f32x4* buffer = (const f32x4*)d_in[1];  // [16,128,128,3] fp32
    f32x4* out = (f32x4*)d_out;                   // [128,16,128,128,3] fp32

    const int grid = NSRC * CHUNKS;               // 143 * 24 = 3432 blocks

    ImageBuffer_86784109183359_kernel<<<grid, BLOCK, 0, stream>>>(inputs, buffer, out);
}